// Round 2
// baseline (200.673 us; speedup 1.0000x reference)
//
#include <hip/hip_runtime.h>
#include <hip/hip_bf16.h>
#include <stdint.h>

typedef __bf16 bf16_t;
typedef __bf16 bf16x8 __attribute__((ext_vector_type(8)));
typedef __bf16 bf16x4 __attribute__((ext_vector_type(4)));
typedef float  f32x4  __attribute__((ext_vector_type(4)));

#define DIM   1024
#define BATCH 8
#define NTOK  (BATCH * DIM)   /* 8192 */
#define SCALE 0.03125f        /* 1/sqrt(1024) */
#define NT    32              /* K / 32 for all GEMMs (K = 1024) */

// ---------------- f32 -> bf16 convert (vectorized) ----------------
__global__ void k_cvt(const float* __restrict__ in, bf16_t* __restrict__ out, int n4) {
    int i = blockIdx.x * blockDim.x + threadIdx.x;
    if (i < n4) {
        const float4 v = reinterpret_cast<const float4*>(in)[i];
        bf16x4 o;
        o.x = (bf16_t)v.x; o.y = (bf16_t)v.y; o.z = (bf16_t)v.z; o.w = (bf16_t)v.w;
        reinterpret_cast<bf16x4*>(out)[i] = o;
    }
}

// ------------- W_eff^T[e][d] = bf16( sum_n w[n][d][e] ) -------------
__global__ void k_weff(const float* __restrict__ w, bf16_t* __restrict__ wt) {
    __shared__ float tile[32][33];
    const int tx = threadIdx.x & 31;
    const int ty = threadIdx.x >> 5;           // 0..7
    const int d0 = blockIdx.x * 32;
    const int e0 = blockIdx.y * 32;
#pragma unroll
    for (int r = 0; r < 4; ++r) {
        const int d = d0 + r * 8 + ty;
        const int e = e0 + tx;
        tile[r * 8 + ty][tx] =
            w[d * 1024 + e] + w[1048576 + d * 1024 + e] + w[2097152 + d * 1024 + e];
    }
    __syncthreads();
#pragma unroll
    for (int r = 0; r < 4; ++r) {
        const int e = e0 + r * 8 + ty;
        const int d = d0 + tx;
        wt[e * 1024 + d] = (bf16_t)tile[tx][r * 8 + ty];
    }
}

// ------------- WqT[d][e] = bf16( Wqkv[e*1024 + d] ), e,d in [0,1024) -------------
__global__ void k_trans(const float* __restrict__ in, bf16_t* __restrict__ out) {
    __shared__ float tile[32][33];
    const int tx = threadIdx.x & 31;
    const int ty = threadIdx.x >> 5;
    const int e0 = blockIdx.x * 32;
    const int d0 = blockIdx.y * 32;
#pragma unroll
    for (int r = 0; r < 4; ++r)
        tile[r * 8 + ty][tx] = in[(long)(e0 + r * 8 + ty) * 1024 + d0 + tx];
    __syncthreads();
#pragma unroll
    for (int r = 0; r < 4; ++r)
        out[(long)(d0 + r * 8 + ty) * 1024 + e0 + tx] = (bf16_t)tile[tx][r * 8 + ty];
}

// ------------- bqw[n] = sum_d bq[d] * WeffT[n][d] -------------
__global__ void k_bqw(const float* __restrict__ bq, const bf16_t* __restrict__ wtb,
                      float* __restrict__ bqw) {
    const int n = blockIdx.x * 256 + threadIdx.x;
    float s = 0.f;
    for (int d = 0; d < 1024; ++d) s += bq[d] * (float)wtb[n * 1024 + d];
    bqw[n] = s;
}

// ---------------- 128x128 tile bf16 MFMA GEMM (kept for the small B' GEMM) ------
// C[m][n] = sum_k A[m][k] * B[n][k];  MODE 0: oB[m*1024+n] = bf16(acc)
template<int MODE>
__global__ __launch_bounds__(256)
void k_gemm(const bf16_t* __restrict__ A, const bf16_t* __restrict__ B, int K,
            const float* __restrict__ bias,
            bf16_t* __restrict__ oQ, bf16_t* __restrict__ oK,
            float* __restrict__ oF, bf16_t* __restrict__ oB)
{
    __shared__ __align__(16) bf16_t As[128 * 32];
    __shared__ __align__(16) bf16_t Bs[128 * 32];

    const int tid  = threadIdx.x;
    const int wave = tid >> 6;
    const int lane = tid & 63;
    const int wr = wave >> 1, wc = wave & 1;
    const int lhi = lane >> 4, llo = lane & 15;

    const int bm = blockIdx.x * 128;
    const int bn = blockIdx.y * 128;

    f32x4 acc[4][4];
    const f32x4 fz = {0.f, 0.f, 0.f, 0.f};
#pragma unroll
    for (int i = 0; i < 4; ++i)
#pragma unroll
        for (int j = 0; j < 4; ++j) acc[i][j] = fz;

    for (int k0 = 0; k0 < K; k0 += 32) {
#pragma unroll
        for (int i = 0; i < 2; ++i) {
            const int c  = wave * 128 + i * 64 + lane;
            const int r  = c >> 2;
            const int cc = (c & 3) << 3;
            const long ga = (long)(bm + r) * K + (k0 + cc);
            const long gb = (long)(bn + r) * K + (k0 + cc);
            const int lbase = (wave * 128 + i * 64) << 3;
            __builtin_amdgcn_global_load_lds(
                (const __attribute__((address_space(1))) uint32_t*)(A + ga),
                (__attribute__((address_space(3))) uint32_t*)(&As[lbase]), 16, 0, 0);
            __builtin_amdgcn_global_load_lds(
                (const __attribute__((address_space(1))) uint32_t*)(B + gb),
                (__attribute__((address_space(3))) uint32_t*)(&Bs[lbase]), 16, 0, 0);
        }
        __syncthreads();

        bf16x8 af[4], bfr[4];
#pragma unroll
        for (int mi = 0; mi < 4; ++mi)
            af[mi] = *reinterpret_cast<const bf16x8*>(&As[(wr * 64 + mi * 16 + llo) * 32 + lhi * 8]);
#pragma unroll
        for (int ni = 0; ni < 4; ++ni)
            bfr[ni] = *reinterpret_cast<const bf16x8*>(&Bs[(wc * 64 + ni * 16 + llo) * 32 + lhi * 8]);
#pragma unroll
        for (int mi = 0; mi < 4; ++mi)
#pragma unroll
            for (int ni = 0; ni < 4; ++ni)
                acc[mi][ni] = __builtin_amdgcn_mfma_f32_16x16x32_bf16(af[mi], bfr[ni], acc[mi][ni], 0, 0, 0);
        __syncthreads();
    }

#pragma unroll
    for (int mi = 0; mi < 4; ++mi) {
        const int r0 = bm + wr * 64 + mi * 16 + lhi * 4;
#pragma unroll
        for (int ni = 0; ni < 4; ++ni) {
            const int cg = bn + wc * 64 + ni * 16 + llo;
            const f32x4 v = acc[mi][ni];
#pragma unroll
            for (int j = 0; j < 4; ++j) {
                const long row = r0 + j;
                oB[row * DIM + cg] = (bf16_t)v[j];
            }
        }
    }
}

// ================= 256x256 tile, ring-4 deep pipeline, swizzled LDS =============
// C[m][n] = sum_k A[m][k] * B[n][k], K=1024 fixed (NT=32 tiles of BK=32).
// 8 waves (2Mx4N), per-wave 128x64 output. LDS: 4 ring slots x (A 16KB + B 16KB).
// Swizzle (within 128B = 8 chunks of 16B): u = ((r&1)<<2 | c) ^ ((r>>1)&7).
// Staging writes linearly (global_load_lds) from inverse-swizzled global src.
// MODE 1: qkv projection epilogue (bn>>10 routes qw/k/v, bias add)
// MODE 2: oF[z*1M + m*1024 + n] += SCALE * acc
__device__ __forceinline__ int swz_addr(int r, int cIdx) {
    const int r2 = r >> 1;
    return (r2 << 7) | (((((r & 1) << 2) | cIdx) ^ (r2 & 7)) << 4);
}

template<int MODE>
__global__ __launch_bounds__(512, 2)
void k_gemm256(const bf16_t* __restrict__ A, const bf16_t* __restrict__ B,
               const float* __restrict__ bias0, const float* __restrict__ bias1,
               bf16_t* __restrict__ oQW, bf16_t* __restrict__ oK,
               float* __restrict__ oF)
{
    __shared__ __align__(16) unsigned char slds[131072];   // 4 x 32KB ring slots

    const int tid  = threadIdx.x;
    const int wave = tid >> 6, lane = tid & 63;
    const int wr = wave >> 2, wc = wave & 3;
    const int llo = lane & 15, lhi = lane >> 4;
    const int bm = blockIdx.x * 256, bn = blockIdx.y * 256;
    const long zoff = (MODE == 2) ? (long)blockIdx.z * 1048576 : 0;

    auto stage = [&](int t) {
        const int rb = t & 3;
        const int k0 = t << 5;
#pragma unroll
        for (int j = 0; j < 4; ++j) {
            const int C  = j * 512 + tid;          // 0..2047: A chunks then B chunks
            const int Cm = C & 1023;
            const int r2 = Cm >> 3, s = Cm & 7;
            const int u  = s ^ (r2 & 7);           // inverse swizzle (involution)
            const int r  = (r2 << 1) | (u >> 2);
            const int ce = (u & 3) << 3;
            const bf16_t* src = (C < 1024)
                ? A + zoff + (long)(bm + r) * 1024 + k0 + ce
                : B + zoff + (long)(bn + r) * 1024 + k0 + ce;
            unsigned char* dst = &slds[(rb << 15) + (((j << 9) + (wave << 6)) << 4)];
            __builtin_amdgcn_global_load_lds(
                (const __attribute__((address_space(1))) uint32_t*)src,
                (__attribute__((address_space(3))) uint32_t*)dst, 16, 0, 0);
        }
    };

    f32x4 acc[8][4];
    const f32x4 fz = {0.f, 0.f, 0.f, 0.f};
#pragma unroll
    for (int i = 0; i < 8; ++i)
#pragma unroll
        for (int j = 0; j < 4; ++j) acc[i][j] = fz;

    stage(0); stage(1); stage(2);

    for (int t = 0; t < NT; ++t) {
        // counted vmcnt: guarantee tile t landed, keep later tiles in flight
        if (t + 3 < NT) {
            stage(t + 3);
            asm volatile("s_waitcnt vmcnt(8)" ::: "memory");
        } else if (t + 2 < NT) {
            asm volatile("s_waitcnt vmcnt(8)" ::: "memory");
        } else if (t + 1 < NT) {
            asm volatile("s_waitcnt vmcnt(4)" ::: "memory");
        } else {
            asm volatile("s_waitcnt vmcnt(0)" ::: "memory");
        }
        __builtin_amdgcn_s_barrier();

        const unsigned char* baA = &slds[(t & 3) << 15];
        const unsigned char* baB = baA + 16384;
        bf16x8 af[8], bfv[4];
#pragma unroll
        for (int mi = 0; mi < 8; ++mi)
            af[mi] = *reinterpret_cast<const bf16x8*>(baA + swz_addr(wr * 128 + mi * 16 + llo, lhi));
#pragma unroll
        for (int ni = 0; ni < 4; ++ni)
            bfv[ni] = *reinterpret_cast<const bf16x8*>(baB + swz_addr(wc * 64 + ni * 16 + llo, lhi));
#pragma unroll
        for (int mi = 0; mi < 8; ++mi)
#pragma unroll
            for (int ni = 0; ni < 4; ++ni)
                acc[mi][ni] = __builtin_amdgcn_mfma_f32_16x16x32_bf16(af[mi], bfv[ni], acc[mi][ni], 0, 0, 0);
        __builtin_amdgcn_s_barrier();
    }

    // ---------------- epilogue ----------------
    const int sec = (MODE == 1) ? (bn >> 10) : 0;
#pragma unroll
    for (int mi = 0; mi < 8; ++mi) {
        const long r0 = bm + wr * 128 + mi * 16 + lhi * 4;
#pragma unroll
        for (int ni = 0; ni < 4; ++ni) {
            const int cg = bn + wc * 64 + ni * 16 + llo;
            const f32x4 v = acc[mi][ni];
            if (MODE == 1) {
                const float bb = (sec == 0) ? bias0[cg] : bias1[cg];
                const int c1 = cg & 1023;
#pragma unroll
                for (int j = 0; j < 4; ++j) {
                    const long idx = (r0 + j) * 1024 + c1;
                    const float val = v[j] + bb;
                    if (sec == 0)      oQW[idx] = (bf16_t)val;
                    else if (sec == 1) oK[idx] = (bf16_t)val;
                    else               oF[idx] = val;
                }
            } else {
                const long base = (long)blockIdx.z * 1048576;
#pragma unroll
                for (int j = 0; j < 4; ++j) {
                    const long idx = base + (r0 + j) * 1024 + cg;
                    oF[idx] = oF[idx] + SCALE * v[j];
                }
            }
        }
    }
}

extern "C" void kernel_launch(void* const* d_in, const int* in_sizes, int n_in,
                              void* d_out, int out_size, void* d_ws, size_t ws_size,
                              hipStream_t stream) {
    const float* x    = (const float*)d_in[0];
    const float* Wqkv = (const float*)d_in[1];
    const float* bqkv = (const float*)d_in[2];
    const float* w    = (const float*)d_in[3];
    float* out = (float*)d_out;

    // workspace layout (54 MiB + 64 KiB)
    char* ws = (char*)d_ws;
    bf16_t* xb   = (bf16_t*)(ws);                          // 16 MiB
    bf16_t* wbig = (bf16_t*)(ws + (16l << 20));            // 6 MiB: rows 0:1024 = B', 1024:3072 = Wk,Wv
    float*  bqw  = (float*) (ws + (22l << 20));            // 4 KiB (64 KiB reserved)
    bf16_t* kb   = (bf16_t*)(ws + (22l << 20) + 65536);    // 16 MiB
    bf16_t* qwb  = (bf16_t*)(ws + (38l << 20) + 65536);    // 16 MiB
    bf16_t* wtb  = qwb;              // 2 MiB WeffT (dead before qwb is written)
    bf16_t* wqt  = qwb + 1048576;    // 2 MiB WqT  (dead before qwb is written)
    if (ws_size < (size_t)(54l << 20) + 65536) return;

    // preamble: converts, transpose-sum, bias fold
    k_cvt  <<<8192, 256, 0, stream>>>(x, xb, 2097152);
    k_cvt  <<<2048, 256, 0, stream>>>(Wqkv + 1048576, wbig + 1048576, 524288);
    k_weff <<<dim3(32, 32), 256, 0, stream>>>(w, wtb);
    k_trans<<<dim3(32, 32), 256, 0, stream>>>(Wqkv, wqt);
    k_bqw  <<<4, 256, 0, stream>>>(bqkv, wtb, bqw);

    // B' = WeffT @ WqT^T  (small 1024^3 GEMM) -> wbig rows [0,1024)
    k_gemm<0><<<dim3(8, 8), 256, 0, stream>>>(wtb, wqt, 1024, nullptr,
                                              nullptr, nullptr, nullptr, wbig);
    // fused projection: [qw | k | v] = x @ wbig^T + [bqw | bk | bv]
    k_gemm256<1><<<dim3(32, 12), 512, 0, stream>>>(xb, wbig, bqw, bqkv, qwb, kb, out);
    // scores: out += SCALE * qw @ k^T (per batch)
    k_gemm256<2><<<dim3(4, 4, 8), 512, 0, stream>>>(qwb, kb, nullptr, nullptr,
                                                    nullptr, nullptr, out);
}

// Round 3
// 171.407 us; speedup vs baseline: 1.1707x; 1.1707x over previous
//
#include <hip/hip_runtime.h>
#include <hip/hip_bf16.h>
#include <stdint.h>

typedef __bf16 bf16_t;
typedef __bf16 bf16x8 __attribute__((ext_vector_type(8)));
typedef __bf16 bf16x4 __attribute__((ext_vector_type(4)));
typedef float  f32x4  __attribute__((ext_vector_type(4)));

#define DIM   1024
#define BATCH 8
#define NTOK  (BATCH * DIM)   /* 8192 */
#define SCALE 0.03125f        /* 1/sqrt(1024) */
#define NT    32              /* K / 32 (K = 1024) */

// ---------------- f32 -> bf16 convert (vectorized) ----------------
__global__ void k_cvt(const float* __restrict__ in, bf16_t* __restrict__ out, int n4) {
    int i = blockIdx.x * blockDim.x + threadIdx.x;
    if (i < n4) {
        const float4 v = reinterpret_cast<const float4*>(in)[i];
        bf16x4 o;
        o.x = (bf16_t)v.x; o.y = (bf16_t)v.y; o.z = (bf16_t)v.z; o.w = (bf16_t)v.w;
        reinterpret_cast<bf16x4*>(out)[i] = o;
    }
}

// ------------- W_eff^T[e][d] = bf16( sum_n w[n][d][e] ) -------------
__global__ void k_weff(const float* __restrict__ w, bf16_t* __restrict__ wt) {
    __shared__ float tile[32][33];
    const int tx = threadIdx.x & 31;
    const int ty = threadIdx.x >> 5;           // 0..7
    const int d0 = blockIdx.x * 32;
    const int e0 = blockIdx.y * 32;
#pragma unroll
    for (int r = 0; r < 4; ++r) {
        const int d = d0 + r * 8 + ty;
        const int e = e0 + tx;
        tile[r * 8 + ty][tx] =
            w[d * 1024 + e] + w[1048576 + d * 1024 + e] + w[2097152 + d * 1024 + e];
    }
    __syncthreads();
#pragma unroll
    for (int r = 0; r < 4; ++r) {
        const int e = e0 + r * 8 + ty;
        const int d = d0 + tx;
        wt[e * 1024 + d] = (bf16_t)tile[tx][r * 8 + ty];
    }
}

// ------------- WqT[d][e] = bf16( Wqkv[e*1024 + d] ) -------------
__global__ void k_trans(const float* __restrict__ in, bf16_t* __restrict__ out) {
    __shared__ float tile[32][33];
    const int tx = threadIdx.x & 31;
    const int ty = threadIdx.x >> 5;
    const int e0 = blockIdx.x * 32;
    const int d0 = blockIdx.y * 32;
#pragma unroll
    for (int r = 0; r < 4; ++r)
        tile[r * 8 + ty][tx] = in[(long)(e0 + r * 8 + ty) * 1024 + d0 + tx];
    __syncthreads();
#pragma unroll
    for (int r = 0; r < 4; ++r)
        out[(long)(d0 + r * 8 + ty) * 1024 + e0 + tx] = (bf16_t)tile[tx][r * 8 + ty];
}

// ------------- bqw[n] = sum_d bq[d] * WeffT[n][d] -------------
__global__ void k_bqw(const float* __restrict__ bq, const bf16_t* __restrict__ wtb,
                      float* __restrict__ bqw) {
    const int n = blockIdx.x * 256 + threadIdx.x;
    float s = 0.f;
    for (int d = 0; d < 1024; ++d) s += bq[d] * (float)wtb[n * 1024 + d];
    bqw[n] = s;
}

// ---------------- 128x128 tile bf16 MFMA GEMM (small B' GEMM only) ------
// C[m][n] = sum_k A[m][k] * B[n][k];  oB[m*1024+n] = bf16(acc)
__global__ __launch_bounds__(256)
void k_gemm128(const bf16_t* __restrict__ A, const bf16_t* __restrict__ B, int K,
               bf16_t* __restrict__ oB)
{
    __shared__ __align__(16) bf16_t As[128 * 32];
    __shared__ __align__(16) bf16_t Bs[128 * 32];

    const int tid  = threadIdx.x;
    const int wave = tid >> 6;
    const int lane = tid & 63;
    const int wr = wave >> 1, wc = wave & 1;
    const int lhi = lane >> 4, llo = lane & 15;

    const int bm = blockIdx.x * 128;
    const int bn = blockIdx.y * 128;

    f32x4 acc[4][4];
    const f32x4 fz = {0.f, 0.f, 0.f, 0.f};
#pragma unroll
    for (int i = 0; i < 4; ++i)
#pragma unroll
        for (int j = 0; j < 4; ++j) acc[i][j] = fz;

    for (int k0 = 0; k0 < K; k0 += 32) {
#pragma unroll
        for (int i = 0; i < 2; ++i) {
            const int c  = wave * 128 + i * 64 + lane;
            const int r  = c >> 2;
            const int cc = (c & 3) << 3;
            const long ga = (long)(bm + r) * K + (k0 + cc);
            const long gb = (long)(bn + r) * K + (k0 + cc);
            const int lbase = (wave * 128 + i * 64) << 3;
            __builtin_amdgcn_global_load_lds(
                (const __attribute__((address_space(1))) uint32_t*)(A + ga),
                (__attribute__((address_space(3))) uint32_t*)(&As[lbase]), 16, 0, 0);
            __builtin_amdgcn_global_load_lds(
                (const __attribute__((address_space(1))) uint32_t*)(B + gb),
                (__attribute__((address_space(3))) uint32_t*)(&Bs[lbase]), 16, 0, 0);
        }
        __syncthreads();

        bf16x8 af[4], bfr[4];
#pragma unroll
        for (int mi = 0; mi < 4; ++mi)
            af[mi] = *reinterpret_cast<const bf16x8*>(&As[(wr * 64 + mi * 16 + llo) * 32 + lhi * 8]);
#pragma unroll
        for (int ni = 0; ni < 4; ++ni)
            bfr[ni] = *reinterpret_cast<const bf16x8*>(&Bs[(wc * 64 + ni * 16 + llo) * 32 + lhi * 8]);
#pragma unroll
        for (int mi = 0; mi < 4; ++mi)
#pragma unroll
            for (int ni = 0; ni < 4; ++ni)
                acc[mi][ni] = __builtin_amdgcn_mfma_f32_16x16x32_bf16(af[mi], bfr[ni], acc[mi][ni], 0, 0, 0);
        __syncthreads();
    }

#pragma unroll
    for (int mi = 0; mi < 4; ++mi) {
        const int r0 = bm + wr * 64 + mi * 16 + lhi * 4;
#pragma unroll
        for (int ni = 0; ni < 4; ++ni) {
            const int cg = bn + wc * 64 + ni * 16 + llo;
            const f32x4 v = acc[mi][ni];
#pragma unroll
            for (int j = 0; j < 4; ++j)
                oB[(long)(r0 + j) * DIM + cg] = (bf16_t)v[j];
        }
    }
}

// ================= BM=128 x BN_, ring-3 pipelined, swizzled LDS =================
// C[m][n] = sum_k A[m][k] * B[n][k], K=1024 (NT=32 tiles of BK=32).
// 8 waves (2M x 4N): per-wave 64 x BN_/4 output (4 x NF fragments).
// Ring-3 slots of (128 + BN_)*64 B; stage(t+2) issued inside tile t's window
// (slot idle since tile t-1's reads, separated by tile t's top barrier).
// Steady-state s_waitcnt vmcnt(2) at tile top: tile t landed, t+1 in flight.
// Swizzle (within 128B = 8 x 16B chunks): u = ((r&1)<<2 | c) ^ ((r>>1)&7);
// staging writes linearly from inverse-swizzled global src (involution).
// MODE 1 (BN_=192): qkv projection epilogue (per-element q/k/v routing + bias)
// MODE 2 (BN_=128): oF[z + m*1024 + n] += SCALE * acc
__device__ __forceinline__ int swz_addr(int r, int cIdx) {
    const int r2 = r >> 1;
    return (r2 << 7) | (((((r & 1) << 2) | cIdx) ^ (r2 & 7)) << 4);
}

template<int BN_, int MODE>
__global__ __launch_bounds__(512, 4)
void k_pipe(const bf16_t* __restrict__ A, const bf16_t* __restrict__ B,
            const float* __restrict__ bqw, const float* __restrict__ bqkv,
            bf16_t* __restrict__ oQW, bf16_t* __restrict__ oK,
            float* __restrict__ oF)
{
    constexpr int NF   = BN_ / 64;           // n-frags per wave (3 or 2)
    constexpr int SLOT = (128 + BN_) * 64;   // bytes per ring slot
    constexpr int TOTC = (128 + BN_) * 4;    // 16B chunks per tile (A then B)
    constexpr int NJ   = (TOTC + 511) / 512; // stage passes per thread
    __shared__ __align__(16) unsigned char slds[3 * SLOT];

    const int tid  = threadIdx.x;
    const int wave = tid >> 6, lane = tid & 63;
    const int wr = wave >> 2, wc = wave & 3;
    const int llo = lane & 15, lhi = lane >> 4;
    const int bm = blockIdx.x * 128;
    const int bn = blockIdx.y * BN_;
    const long z = (MODE == 2) ? (long)blockIdx.z * 1048576 : 0;

    auto stage = [&](int t) {
        const int slot = (t % 3) * SLOT;
        const int k0 = t << 5;
#pragma unroll
        for (int j = 0; j < NJ; ++j) {
            if (NJ == 3 && j == 2 && wave >= 4) break;   // wave-uniform guard
            const int C   = j * 512 + tid;
            const bool inA = (C < 512);
            const int Cm  = inA ? C : C - 512;
            const int r2 = Cm >> 3, s8 = Cm & 7;
            const int u  = s8 ^ (r2 & 7);                // inverse swizzle
            const int r  = (r2 << 1) | (u >> 2);
            const int ce = (u & 3) << 3;
            const bf16_t* src = inA ? (A + z + (long)(bm + r) * 1024 + k0 + ce)
                                    : (B + z + (long)(bn + r) * 1024 + k0 + ce);
            const int group = j * 512 + wave * 64;       // wave-uniform
            const int goff  = (group < 512) ? (group << 4)
                                            : 8192 + ((group - 512) << 4);
            __builtin_amdgcn_global_load_lds(
                (const __attribute__((address_space(1))) uint32_t*)src,
                (__attribute__((address_space(3))) uint32_t*)(&slds[slot + goff]),
                16, 0, 0);
        }
    };

    f32x4 acc[4][NF];
    const f32x4 fz = {0.f, 0.f, 0.f, 0.f};
#pragma unroll
    for (int i = 0; i < 4; ++i)
#pragma unroll
        for (int j = 0; j < NF; ++j) acc[i][j] = fz;

    stage(0); stage(1);

    for (int t = 0; t < NT; ++t) {
        if (t < NT - 1) asm volatile("s_waitcnt vmcnt(2)" ::: "memory");
        else            asm volatile("s_waitcnt vmcnt(0)" ::: "memory");
        __builtin_amdgcn_s_barrier();

        const unsigned char* ba = &slds[(t % 3) * SLOT];
        bf16x8 af[4], bfv[NF];
#pragma unroll
        for (int mi = 0; mi < 4; ++mi)
            af[mi] = *reinterpret_cast<const bf16x8*>(ba + swz_addr(wr * 64 + mi * 16 + llo, lhi));
#pragma unroll
        for (int ni = 0; ni < NF; ++ni)
            bfv[ni] = *reinterpret_cast<const bf16x8*>(ba + 8192 + swz_addr(wc * (BN_ / 4) + ni * 16 + llo, lhi));

        if (t < NT - 2) stage(t + 2);

        __builtin_amdgcn_s_setprio(1);
#pragma unroll
        for (int mi = 0; mi < 4; ++mi)
#pragma unroll
            for (int ni = 0; ni < NF; ++ni)
                acc[mi][ni] = __builtin_amdgcn_mfma_f32_16x16x32_bf16(af[mi], bfv[ni], acc[mi][ni], 0, 0, 0);
        __builtin_amdgcn_s_setprio(0);
    }

    // ---------------- epilogue ----------------
#pragma unroll
    for (int mi = 0; mi < 4; ++mi) {
        const long r0 = bm + wr * 64 + mi * 16 + lhi * 4;
#pragma unroll
        for (int ni = 0; ni < NF; ++ni) {
            const int cg = bn + wc * (BN_ / 4) + ni * 16 + llo;
            const f32x4 v = acc[mi][ni];
            if (MODE == 1) {
                const int sec = cg >> 10;
                const int c1  = cg & 1023;
                const float bb = (sec == 0) ? bqw[cg] : bqkv[cg];
#pragma unroll
                for (int j = 0; j < 4; ++j) {
                    const long idx = (r0 + j) * 1024 + c1;
                    const float val = v[j] + bb;
                    if (sec == 0)      oQW[idx] = (bf16_t)val;
                    else if (sec == 1) oK[idx] = (bf16_t)val;
                    else               oF[idx] = val;
                }
            } else {
#pragma unroll
                for (int j = 0; j < 4; ++j) {
                    const long idx = z + (r0 + j) * 1024 + cg;
                    oF[idx] = oF[idx] + SCALE * v[j];
                }
            }
        }
    }
}

extern "C" void kernel_launch(void* const* d_in, const int* in_sizes, int n_in,
                              void* d_out, int out_size, void* d_ws, size_t ws_size,
                              hipStream_t stream) {
    const float* x    = (const float*)d_in[0];
    const float* Wqkv = (const float*)d_in[1];
    const float* bqkv = (const float*)d_in[2];
    const float* w    = (const float*)d_in[3];
    float* out = (float*)d_out;

    // workspace layout
    char* ws = (char*)d_ws;
    bf16_t* xb   = (bf16_t*)(ws);                          // 16 MiB
    bf16_t* wbig = (bf16_t*)(ws + (16l << 20));            // 6 MiB: rows 0:1024 = B', 1024:3072 = Wk,Wv
    float*  bqw  = (float*) (ws + (22l << 20));            // 4 KiB (64 KiB reserved)
    bf16_t* kb   = (bf16_t*)(ws + (22l << 20) + 65536);    // 16 MiB
    bf16_t* qwb  = (bf16_t*)(ws + (38l << 20) + 65536);    // 16 MiB
    bf16_t* wtb  = qwb;              // 2 MiB WeffT (dead before qwb is written)
    bf16_t* wqt  = qwb + 1048576;    // 2 MiB WqT  (dead before qwb is written)
    if (ws_size < (size_t)(54l << 20) + 65536) return;

    // preamble: converts, transpose-sum, bias fold
    k_cvt  <<<8192, 256, 0, stream>>>(x, xb, 2097152);
    k_cvt  <<<2048, 256, 0, stream>>>(Wqkv + 1048576, wbig + 1048576, 524288);
    k_weff <<<dim3(32, 32), 256, 0, stream>>>(w, wtb);
    k_trans<<<dim3(32, 32), 256, 0, stream>>>(Wqkv, wqt);
    k_bqw  <<<4, 256, 0, stream>>>(bqkv, wtb, bqw);

    // B' = WeffT @ WqT^T  (small 1024^3 GEMM) -> wbig rows [0,1024)
    k_gemm128<<<dim3(8, 8), 256, 0, stream>>>(wtb, wqt, 1024, wbig);

    // fused projection: [qw | k | v] = x @ wbig^T + [bqw | bk | bv]
    // grid 64x16 = 1024 blocks @ 2 blocks/CU = exactly 512 slots, no tail
    k_pipe<192, 1><<<dim3(64, 16), 512, 0, stream>>>(xb, wbig, bqw, bqkv, qwb, kb, out);

    // scores: out += SCALE * qw @ k^T (per batch); 512 blocks, full machine
    k_pipe<128, 2><<<dim3(8, 8, 8), 512, 0, stream>>>(qwb, kb, nullptr, nullptr,
                                                      nullptr, nullptr, out);
}

// Round 4
// 138.324 us; speedup vs baseline: 1.4507x; 1.2392x over previous
//
#include <hip/hip_runtime.h>
#include <hip/hip_bf16.h>
#include <stdint.h>

typedef __bf16 bf16_t;
typedef __bf16 bf16x8 __attribute__((ext_vector_type(8)));
typedef __bf16 bf16x4 __attribute__((ext_vector_type(4)));
typedef float  f32x4  __attribute__((ext_vector_type(4)));

#define DIM   1024
#define BATCH 8
#define NTOK  (BATCH * DIM)   /* 8192 */
#define SCALE 0.03125f        /* 1/sqrt(1024) */

// ---------------- f32 -> bf16 convert (vectorized) ----------------
__global__ void k_cvt(const float* __restrict__ in, bf16_t* __restrict__ out, int n4) {
    int i = blockIdx.x * blockDim.x + threadIdx.x;
    if (i < n4) {
        const float4 v = reinterpret_cast<const float4*>(in)[i];
        bf16x4 o;
        o.x = (bf16_t)v.x; o.y = (bf16_t)v.y; o.z = (bf16_t)v.z; o.w = (bf16_t)v.w;
        reinterpret_cast<bf16x4*>(out)[i] = o;
    }
}

// ------------- W_eff^T[e][d] = bf16( sum_n w[n][d][e] ) -------------
__global__ void k_weff(const float* __restrict__ w, bf16_t* __restrict__ wt) {
    __shared__ float tile[32][33];
    const int tx = threadIdx.x & 31;
    const int ty = threadIdx.x >> 5;           // 0..7
    const int d0 = blockIdx.x * 32;
    const int e0 = blockIdx.y * 32;
#pragma unroll
    for (int r = 0; r < 4; ++r) {
        const int d = d0 + r * 8 + ty;
        const int e = e0 + tx;
        tile[r * 8 + ty][tx] =
            w[d * 1024 + e] + w[1048576 + d * 1024 + e] + w[2097152 + d * 1024 + e];
    }
    __syncthreads();
#pragma unroll
    for (int r = 0; r < 4; ++r) {
        const int e = e0 + r * 8 + ty;
        const int d = d0 + tx;
        wt[e * 1024 + d] = (bf16_t)tile[tx][r * 8 + ty];
    }
}

// ------------- WqT[d][e] = bf16( Wqkv[e*1024 + d] ) -------------
__global__ void k_trans(const float* __restrict__ in, bf16_t* __restrict__ out) {
    __shared__ float tile[32][33];
    const int tx = threadIdx.x & 31;
    const int ty = threadIdx.x >> 5;
    const int e0 = blockIdx.x * 32;
    const int d0 = blockIdx.y * 32;
#pragma unroll
    for (int r = 0; r < 4; ++r)
        tile[r * 8 + ty][tx] = in[(long)(e0 + r * 8 + ty) * 1024 + d0 + tx];
    __syncthreads();
#pragma unroll
    for (int r = 0; r < 4; ++r)
        out[(long)(d0 + r * 8 + ty) * 1024 + e0 + tx] = (bf16_t)tile[tx][r * 8 + ty];
}

// ------------- bqw[n] = sum_d bq[d] * WeffT[n][d]  (wave-parallel) -------------
__global__ void k_bqw(const float* __restrict__ bq, const bf16_t* __restrict__ wtb,
                      float* __restrict__ bqw) {
    const int wave = threadIdx.x >> 6, lane = threadIdx.x & 63;
    const int n = blockIdx.x * 4 + wave;
    const bf16_t* row = wtb + (long)n * 1024;
    float s = 0.f;
#pragma unroll
    for (int c = 0; c < 2; ++c) {
        const int d0 = (lane + c * 64) * 8;
        const bf16x8 v = *reinterpret_cast<const bf16x8*>(row + d0);
#pragma unroll
        for (int e = 0; e < 8; ++e) s += bq[d0 + e] * (float)v[e];
    }
#pragma unroll
    for (int off = 32; off; off >>= 1) s += __shfl_down(s, off);
    if (lane == 0) bqw[n] = s;
}

// ---------------- 128x128 tile bf16 MFMA GEMM (small B' GEMM only) ------
__global__ __launch_bounds__(256)
void k_gemm128(const bf16_t* __restrict__ A, const bf16_t* __restrict__ B, int K,
               bf16_t* __restrict__ oB)
{
    __shared__ __align__(16) bf16_t As[128 * 32];
    __shared__ __align__(16) bf16_t Bs[128 * 32];

    const int tid  = threadIdx.x;
    const int wave = tid >> 6;
    const int lane = tid & 63;
    const int wr = wave >> 1, wc = wave & 1;
    const int lhi = lane >> 4, llo = lane & 15;

    const int bm = blockIdx.x * 128;
    const int bn = blockIdx.y * 128;

    f32x4 acc[4][4];
    const f32x4 fz = {0.f, 0.f, 0.f, 0.f};
#pragma unroll
    for (int i = 0; i < 4; ++i)
#pragma unroll
        for (int j = 0; j < 4; ++j) acc[i][j] = fz;

    for (int k0 = 0; k0 < K; k0 += 32) {
#pragma unroll
        for (int i = 0; i < 2; ++i) {
            const int c  = wave * 128 + i * 64 + lane;
            const int r  = c >> 2;
            const int cc = (c & 3) << 3;
            const long ga = (long)(bm + r) * K + (k0 + cc);
            const long gb = (long)(bn + r) * K + (k0 + cc);
            const int lbase = (wave * 128 + i * 64) << 3;
            __builtin_amdgcn_global_load_lds(
                (const __attribute__((address_space(1))) uint32_t*)(A + ga),
                (__attribute__((address_space(3))) uint32_t*)(&As[lbase]), 16, 0, 0);
            __builtin_amdgcn_global_load_lds(
                (const __attribute__((address_space(1))) uint32_t*)(B + gb),
                (__attribute__((address_space(3))) uint32_t*)(&Bs[lbase]), 16, 0, 0);
        }
        __syncthreads();

        bf16x8 af[4], bfr[4];
#pragma unroll
        for (int mi = 0; mi < 4; ++mi)
            af[mi] = *reinterpret_cast<const bf16x8*>(&As[(wr * 64 + mi * 16 + llo) * 32 + lhi * 8]);
#pragma unroll
        for (int ni = 0; ni < 4; ++ni)
            bfr[ni] = *reinterpret_cast<const bf16x8*>(&Bs[(wc * 64 + ni * 16 + llo) * 32 + lhi * 8]);
#pragma unroll
        for (int mi = 0; mi < 4; ++mi)
#pragma unroll
            for (int ni = 0; ni < 4; ++ni)
                acc[mi][ni] = __builtin_amdgcn_mfma_f32_16x16x32_bf16(af[mi], bfr[ni], acc[mi][ni], 0, 0, 0);
        __syncthreads();
    }

#pragma unroll
    for (int mi = 0; mi < 4; ++mi) {
        const int r0 = bm + wr * 64 + mi * 16 + lhi * 4;
#pragma unroll
        for (int ni = 0; ni < 4; ++ni) {
            const int cg = bn + wc * 64 + ni * 16 + llo;
            const f32x4 v = acc[mi][ni];
#pragma unroll
            for (int j = 0; j < 4; ++j)
                oB[(long)(r0 + j) * DIM + cg] = (bf16_t)v[j];
        }
    }
}

// ========= BM=256 x BN=128, BK=64, ring-3, 2-phase/K-tile deep pipeline =========
// C[m][n] = sum_k A[m][k]*B[n][k], K=1024 (16 tiles of BK=64).
// 8 waves (4M x 2N), per-wave 64x64 (acc[4][4]). LDS: 3 slots x 48KB = 144KB.
// Slot layout: A [256 rows][8 chunks16B], B at +32768 [128][8]; chunk swizzle:
// phys chunk = logical ^ (row & 7)  (involution; staged via inverse-swizzled src).
// Ring-3: stage(t+2) writes slot (t-1)%3, last read at tile t-1 -> race-free.
// vmcnt(6) once per tile (end of phase B): tile t+1's 6 loads landed, t+2's in flight.
#define STG(J) __builtin_amdgcn_global_load_lds( \
    (const __attribute__((address_space(1))) uint32_t*)(sp##J + ke), \
    (__attribute__((address_space(3))) uint32_t*)(sw + d##J##_), 16, 0, 0)

template<int MODE>
__global__ __launch_bounds__(512, 1)
void k_pipe2(const bf16_t* __restrict__ A, const bf16_t* __restrict__ Bp,
             const float* __restrict__ bqw, const float* __restrict__ bqkv,
             bf16_t* __restrict__ oQW, bf16_t* __restrict__ oK,
             float* __restrict__ oF)
{
    constexpr int NTT  = 16;
    constexpr int SLOT = 49152;
    __shared__ __align__(16) unsigned char slds[3 * SLOT];

    const int tid  = threadIdx.x;
    const int wave = tid >> 6, lane = tid & 63;
    const int wm = wave >> 1, wn = wave & 1;
    const int llo = lane & 15, lhi = lane >> 4;
    const int bm = blockIdx.x * 256, bn = blockIdx.y * 128;
    const long z = (MODE == 2) ? ((long)blockIdx.z << 20) : 0;

    // per-thread swizzled staging sources (j=0..3 -> A, j=4..5 -> B)
    const bf16_t *sp0, *sp1, *sp2, *sp3, *sp4, *sp5;
    int d0_, d1_, d2_, d3_, d4_, d5_;
#define MKSRC(J) { \
        const int C = J * 512 + tid; \
        if (J < 4) { const int r = C >> 3, u = (C & 7) ^ (r & 7); \
            sp##J = A + z + (long)(bm + r) * 1024 + (u << 3); } \
        else { const int Cb = C - 2048; const int r = Cb >> 3, u = (Cb & 7) ^ (r & 7); \
            sp##J = Bp + z + (long)(bn + r) * 1024 + (u << 3); } \
        d##J##_ = (J * 512 + wave * 64) << 4; }
    MKSRC(0) MKSRC(1) MKSRC(2) MKSRC(3) MKSRC(4) MKSRC(5)
#undef MKSRC

    f32x4 acc[4][4];
    const f32x4 fz = {0.f, 0.f, 0.f, 0.f};
#pragma unroll
    for (int i = 0; i < 4; ++i)
#pragma unroll
        for (int j = 0; j < 4; ++j) acc[i][j] = fz;

    // prologue: stage tiles 0,1; gate tile 0
    {
        unsigned char* sw = &slds[0];
        long ke = 0;
        STG(0); STG(1); STG(2); STG(3); STG(4); STG(5);
        sw = &slds[SLOT]; ke = 64;
        STG(0); STG(1); STG(2); STG(3); STG(4); STG(5);
    }
    asm volatile("s_waitcnt vmcnt(6)" ::: "memory");
    __builtin_amdgcn_s_barrier();

    for (int t = 0; t < NTT; ++t) {
        const unsigned char* sb = &slds[(t % 3) * SLOT];
        unsigned char* sw = &slds[((t + 2) % 3) * SLOT];
        const long ke = (long)(t + 2) << 6;
        const bool do_stage = (t + 2 < NTT);

        bf16x8 af[4][2], bfv[4][2];
        // ===== phase A: read A-frags + B-frags 0..1, stage 3, MFMA ni 0..1 =====
#pragma unroll
        for (int mi = 0; mi < 4; ++mi) {
            const int r = wm * 64 + mi * 16 + llo;
#pragma unroll
            for (int ks = 0; ks < 2; ++ks)
                af[mi][ks] = *reinterpret_cast<const bf16x8*>(
                    sb + r * 128 + ((((ks << 2) | lhi) ^ (r & 7)) << 4));
        }
#pragma unroll
        for (int ni = 0; ni < 2; ++ni) {
            const int r = wn * 64 + ni * 16 + llo;
#pragma unroll
            for (int ks = 0; ks < 2; ++ks)
                bfv[ni][ks] = *reinterpret_cast<const bf16x8*>(
                    sb + 32768 + r * 128 + ((((ks << 2) | lhi) ^ (r & 7)) << 4));
        }
        if (do_stage) { STG(0); STG(1); STG(2); }
        __builtin_amdgcn_s_barrier();
        asm volatile("s_waitcnt lgkmcnt(0)" ::: "memory");
        __builtin_amdgcn_sched_barrier(0);
        __builtin_amdgcn_s_setprio(1);
#pragma unroll
        for (int mi = 0; mi < 4; ++mi)
#pragma unroll
            for (int ni = 0; ni < 2; ++ni)
#pragma unroll
                for (int ks = 0; ks < 2; ++ks)
                    acc[mi][ni] = __builtin_amdgcn_mfma_f32_16x16x32_bf16(
                        af[mi][ks], bfv[ni][ks], acc[mi][ni], 0, 0, 0);
        __builtin_amdgcn_s_setprio(0);
        __builtin_amdgcn_s_barrier();

        // ===== phase B: read B-frags 2..3, stage 3, gate, MFMA ni 2..3 =====
#pragma unroll
        for (int ni = 2; ni < 4; ++ni) {
            const int r = wn * 64 + ni * 16 + llo;
#pragma unroll
            for (int ks = 0; ks < 2; ++ks)
                bfv[ni][ks] = *reinterpret_cast<const bf16x8*>(
                    sb + 32768 + r * 128 + ((((ks << 2) | lhi) ^ (r & 7)) << 4));
        }
        if (do_stage) { STG(3); STG(4); STG(5); }
        __builtin_amdgcn_s_barrier();
        asm volatile("s_waitcnt lgkmcnt(0)" ::: "memory");
        __builtin_amdgcn_sched_barrier(0);
        __builtin_amdgcn_s_setprio(1);
#pragma unroll
        for (int mi = 0; mi < 4; ++mi)
#pragma unroll
            for (int ni = 2; ni < 4; ++ni)
#pragma unroll
                for (int ks = 0; ks < 2; ++ks)
                    acc[mi][ni] = __builtin_amdgcn_mfma_f32_16x16x32_bf16(
                        af[mi][ks], bfv[ni][ks], acc[mi][ni], 0, 0, 0);
        __builtin_amdgcn_s_setprio(0);
        if (t + 2 < NTT)      asm volatile("s_waitcnt vmcnt(6)" ::: "memory");
        else if (t + 1 < NTT) asm volatile("s_waitcnt vmcnt(0)" ::: "memory");
        __builtin_amdgcn_s_barrier();
    }

    // ---------------- epilogue ----------------
#pragma unroll
    for (int mi = 0; mi < 4; ++mi) {
        const long r0 = bm + wm * 64 + mi * 16 + lhi * 4;
#pragma unroll
        for (int ni = 0; ni < 4; ++ni) {
            const int cg = bn + wn * 64 + ni * 16 + llo;
            const f32x4 v = acc[mi][ni];
            if (MODE == 1) {
                const int sec = cg >> 10;
                const int c1  = cg & 1023;
                const float bb = (sec == 0) ? bqw[cg] : bqkv[cg];
#pragma unroll
                for (int j = 0; j < 4; ++j) {
                    const long idx = (r0 + j) * 1024 + c1;
                    const float val = v[j] + bb;
                    if (sec == 0)      oQW[idx] = (bf16_t)val;
                    else if (sec == 1) oK[idx] = (bf16_t)val;
                    else               oF[idx] = val;
                }
            } else {
#pragma unroll
                for (int j = 0; j < 4; ++j) {
                    const long idx = z + (r0 + j) * 1024 + cg;
                    oF[idx] = oF[idx] + SCALE * v[j];
                }
            }
        }
    }
}
#undef STG

extern "C" void kernel_launch(void* const* d_in, const int* in_sizes, int n_in,
                              void* d_out, int out_size, void* d_ws, size_t ws_size,
                              hipStream_t stream) {
    const float* x    = (const float*)d_in[0];
    const float* Wqkv = (const float*)d_in[1];
    const float* bqkv = (const float*)d_in[2];
    const float* w    = (const float*)d_in[3];
    float* out = (float*)d_out;

    // workspace layout (54 MiB + 64 KiB)
    char* ws = (char*)d_ws;
    bf16_t* xb   = (bf16_t*)(ws);                          // 16 MiB
    bf16_t* wbig = (bf16_t*)(ws + (16l << 20));            // 6 MiB: rows 0:1024 = B', 1024:3072 = Wk,Wv
    float*  bqw  = (float*) (ws + (22l << 20));            // 4 KiB (64 KiB reserved)
    bf16_t* kb   = (bf16_t*)(ws + (22l << 20) + 65536);    // 16 MiB
    bf16_t* qwb  = (bf16_t*)(ws + (38l << 20) + 65536);    // 16 MiB
    bf16_t* wtb  = qwb;              // 2 MiB WeffT (dead before qwb is written)
    bf16_t* wqt  = qwb + 1048576;    // 2 MiB WqT  (dead before qwb is written)
    if (ws_size < (size_t)(54l << 20) + 65536) return;

    // preamble
    k_cvt  <<<8192, 256, 0, stream>>>(x, xb, 2097152);
    k_cvt  <<<2048, 256, 0, stream>>>(Wqkv + 1048576, wbig + 1048576, 524288);
    k_weff <<<dim3(32, 32), 256, 0, stream>>>(w, wtb);
    k_trans<<<dim3(32, 32), 256, 0, stream>>>(Wqkv, wqt);
    k_bqw  <<<256, 256, 0, stream>>>(bqkv, wtb, bqw);

    // B' = WeffT @ WqT^T -> wbig rows [0,1024)
    k_gemm128<<<dim3(8, 8), 256, 0, stream>>>(wtb, wqt, 1024, wbig);

    // fused projection: [qw | k | v] = x @ wbig^T + bias; 768 blocks = 3 exact rounds
    k_pipe2<1><<<dim3(32, 24), 512, 0, stream>>>(xb, wbig, bqw, bqkv, qwb, kb, out);

    // scores: out += SCALE * qw @ k^T; 256 blocks = 1 exact round
    k_pipe2<2><<<dim3(4, 8, 8), 512, 0, stream>>>(qwb, kb, nullptr, nullptr,
                                                  nullptr, nullptr, out);
}